// Round 1
// baseline (304.412 us; speedup 1.0000x reference)
//
#include <hip/hip_runtime.h>
#include <hip/hip_bf16.h>
#include <stdint.h>

#define NPTS 32768
#define KNBR 32
#define NEDGES (NPTS * KNBR)
#define TM 128          // edges per block (= 4 output rows)
#define AGG_STRIDE 40   // bf16 elems per agg row (80 B, 16B aligned)
#define H_STRIDE 264    // bf16 elems per h row (528 B, 16B aligned, odd dword*4 stride)

typedef __attribute__((ext_vector_type(8))) short short8;
typedef __attribute__((ext_vector_type(4))) float f32x4;
typedef __attribute__((ext_vector_type(4))) unsigned int u32x4;

// round-to-nearest-even f32 -> bf16
__device__ __forceinline__ unsigned short f2bf(float f) {
    unsigned int u = __float_as_uint(f);
    unsigned int r = (u + 0x7FFFu + ((u >> 16) & 1u)) >> 16;
    return (unsigned short)r;
}

// jax.nn.gelu approximate=True (tanh form), via sigmoid identity:
// gelu(x) = x * sigmoid(1.5957691216*(x + 0.044715 x^3))
//         = x / (1 + exp2(-2.30220824 * x*(1 + 0.044715 x^2)))
__device__ __forceinline__ float gelu_tanh(float x) {
    float x2 = x * x;
    float inner = x * fmaf(0.044715f, x2, 1.0f);
    float e = __builtin_amdgcn_exp2f(-2.30220824f * inner);
    return x * __builtin_amdgcn_rcpf(1.0f + e);
}

// ---------------- weight packing into MFMA B-fragment layout (bf16) ----------------
// Fragment for (kstep s, ntile nt): 64 lanes x 8 bf16; lane l supplies
// B[k0+j][nt*16 + (l&15)] with k0 = s*32 + (l>>4)*8, j=0..7 (consecutive).
// u16 layout in ws: [W0: 1024 frags][W1: 8192 frags][W2: 2048 frags], 8 u16 each.
__global__ void pack_w(const float* __restrict__ W0, const float* __restrict__ W1,
                       const float* __restrict__ W2, unsigned short* __restrict__ wp) {
    int tid = blockIdx.x * blockDim.x + threadIdx.x;
    if (tid >= 11264) return;
    unsigned short v[8];
    int l = tid & 63;
    if (tid < 1024) {                 // W0: 6x256, K padded to 32 with zeros
        int nt = tid >> 6;
        int n = nt * 16 + (l & 15);
        int k0 = (l >> 4) << 3;
        #pragma unroll
        for (int j = 0; j < 8; ++j) {
            int k = k0 + j;
            v[j] = f2bf(k < 6 ? W0[k * 256 + n] : 0.0f);
        }
    } else if (tid < 9216) {          // W1: 256x256
        int q = tid - 1024;
        int nt = (q >> 6) & 15;
        int s = q >> 10;
        int n = nt * 16 + (l & 15);
        int k0 = s * 32 + ((l >> 4) << 3);
        #pragma unroll
        for (int j = 0; j < 8; ++j) v[j] = f2bf(W1[(k0 + j) * 256 + n]);
    } else {                          // W2: 256x64
        int q = tid - 9216;
        int nt = (q >> 6) & 3;
        int s = q >> 8;
        int n = nt * 16 + (l & 15);
        int k0 = s * 32 + ((l >> 4) << 3);
        #pragma unroll
        for (int j = 0; j < 8; ++j) v[j] = f2bf(W2[(k0 + j) * 64 + n]);
    }
    unsigned short* o = &wp[tid * 8];
    #pragma unroll
    for (int j = 0; j < 8; ++j) o[j] = v[j];
}

// ---------------- fused GNO kernel ----------------
__global__ __launch_bounds__(256, 2)
void gno_fused(const float* __restrict__ y, const float* __restrict__ x,
               const float* __restrict__ f_y, const int* __restrict__ nbr,
               const float* __restrict__ wts,
               const float* __restrict__ b0, const float* __restrict__ b1,
               const float* __restrict__ b2,
               const unsigned short* __restrict__ wp,
               float* __restrict__ out) {
    __shared__ unsigned short agg_lds[TM * AGG_STRIDE];   // 10 KB
    __shared__ unsigned short h_lds[TM * H_STRIDE];       // 66 KB, reused h0 -> h1

    const int b = blockIdx.x;
    const int tid = threadIdx.x;
    const int l = tid & 63;
    const int w = tid >> 6;          // wave 0..3
    const int lg = l >> 4;           // lane group 0..3
    const int ln = l & 15;
    const int ebase = b * TM;

    // ---- stage agg = [y[nbr[e]] (3), x[e>>5] (3), zeros...] as bf16, K padded to 32
    if (tid < TM) {
        int e = ebase + tid;
        int j = nbr[e];
        int i = e >> 5;              // uniform CSR: row_splits = arange*32
        float a0 = y[j * 3 + 0], a1 = y[j * 3 + 1], a2 = y[j * 3 + 2];
        float a3 = x[i * 3 + 0], a4 = x[i * 3 + 1], a5 = x[i * 3 + 2];
        unsigned int p0 = (unsigned int)f2bf(a0) | ((unsigned int)f2bf(a1) << 16);
        unsigned int p1 = (unsigned int)f2bf(a2) | ((unsigned int)f2bf(a3) << 16);
        unsigned int p2 = (unsigned int)f2bf(a4) | ((unsigned int)f2bf(a5) << 16);
        u32x4 q0 = {p0, p1, p2, 0u};
        u32x4 z  = {0u, 0u, 0u, 0u};
        unsigned short* row = &agg_lds[tid * AGG_STRIDE];
        *(u32x4*)(row +  0) = q0;
        *(u32x4*)(row +  8) = z;
        *(u32x4*)(row + 16) = z;
        *(u32x4*)(row + 24) = z;
    }
    __syncthreads();

    // ---- GEMM1: h0 = gelu(agg @ W0 + b0)   [128 x 256], K=32 (one kstep)
    {
        short8 bw[4];
        float b0v[4];
        #pragma unroll
        for (int n = 0; n < 4; ++n) {
            int nt = 4 * w + n;
            bw[n] = *(const short8*)&wp[(nt * 64 + l) * 8];
            b0v[n] = b0[nt * 16 + ln];
        }
        f32x4 zero = {0.f, 0.f, 0.f, 0.f};
        #pragma unroll
        for (int mt = 0; mt < 8; ++mt) {
            short8 a = *(const short8*)&agg_lds[(mt * 16 + ln) * AGG_STRIDE + lg * 8];
            #pragma unroll
            for (int n = 0; n < 4; ++n) {
                f32x4 c = __builtin_amdgcn_mfma_f32_16x16x32_bf16(a, bw[n], zero, 0, 0, 0);
                int col = (4 * w + n) * 16 + ln;
                #pragma unroll
                for (int i = 0; i < 4; ++i) {
                    float g = gelu_tanh(c[i] + b0v[n]);
                    h_lds[(mt * 16 + lg * 4 + i) * H_STRIDE + col] = f2bf(g);
                }
            }
        }
    }
    __syncthreads();

    // ---- GEMM2: h1 = gelu(h0 @ W1 + b1)   [128 x 256], K=256
    f32x4 acc[8][4];
    #pragma unroll
    for (int mt = 0; mt < 8; ++mt)
        #pragma unroll
        for (int n = 0; n < 4; ++n)
            acc[mt][n] = (f32x4){0.f, 0.f, 0.f, 0.f};

    for (int s = 0; s < 8; ++s) {
        short8 bw[4];
        #pragma unroll
        for (int n = 0; n < 4; ++n)
            bw[n] = *(const short8*)&wp[(1024 + (s * 16 + 4 * w + n) * 64 + l) * 8];
        #pragma unroll
        for (int mt = 0; mt < 8; ++mt) {
            short8 a = *(const short8*)&h_lds[(mt * 16 + ln) * H_STRIDE + s * 32 + lg * 8];
            #pragma unroll
            for (int n = 0; n < 4; ++n)
                acc[mt][n] = __builtin_amdgcn_mfma_f32_16x16x32_bf16(a, bw[n], acc[mt][n], 0, 0, 0);
        }
    }
    __syncthreads();   // everyone done READING h0 before overwriting with h1

    {
        float b1v[4];
        #pragma unroll
        for (int n = 0; n < 4; ++n) b1v[n] = b1[(4 * w + n) * 16 + ln];
        #pragma unroll
        for (int mt = 0; mt < 8; ++mt) {
            #pragma unroll
            for (int n = 0; n < 4; ++n) {
                int col = (4 * w + n) * 16 + ln;
                #pragma unroll
                for (int i = 0; i < 4; ++i) {
                    float g = gelu_tanh(acc[mt][n][i] + b1v[n]);
                    h_lds[(mt * 16 + lg * 4 + i) * H_STRIDE + col] = f2bf(g);
                }
            }
        }
    }
    __syncthreads();

    // ---- GEMM3: rep = h1 @ W2 + b2  [128 x 64]; wave w owns cols [16w,16w+16)
    f32x4 acc3[8];
    #pragma unroll
    for (int mt = 0; mt < 8; ++mt) acc3[mt] = (f32x4){0.f, 0.f, 0.f, 0.f};

    for (int s = 0; s < 8; ++s) {
        short8 bw = *(const short8*)&wp[(9216 + (s * 4 + w) * 64 + l) * 8];
        #pragma unroll
        for (int mt = 0; mt < 8; ++mt) {
            short8 a = *(const short8*)&h_lds[(mt * 16 + ln) * H_STRIDE + s * 32 + lg * 8];
            acc3[mt] = __builtin_amdgcn_mfma_f32_16x16x32_bf16(a, bw, acc3[mt], 0, 0, 0);
        }
    }

    // ---- epilogue: (rep + b2) * f_y[nbr] * wts, then segment-sum (32 edges/row)
    {
        int col = w * 16 + ln;
        float b2v = b2[col];
        float p[4] = {0.f, 0.f, 0.f, 0.f};
        #pragma unroll
        for (int mt = 0; mt < 8; ++mt) {
            #pragma unroll
            for (int i = 0; i < 4; ++i) {
                int el = mt * 16 + lg * 4 + i;
                int e = ebase + el;
                int j = nbr[e];
                float v = acc3[mt][i] + b2v;
                v *= f_y[j * 64 + col] * wts[e];
                p[mt >> 1] += v;   // out row within block = el>>5 = mt>>1
            }
        }
        #pragma unroll
        for (int g = 0; g < 4; ++g) {
            float v = p[g];
            v += __shfl_xor(v, 16, 64);
            v += __shfl_xor(v, 32, 64);
            if (lg == 0) out[(b * 4 + g) * 64 + col] = v;
        }
    }
}

extern "C" void kernel_launch(void* const* d_in, const int* in_sizes, int n_in,
                              void* d_out, int out_size, void* d_ws, size_t ws_size,
                              hipStream_t stream) {
    const float* y   = (const float*)d_in[0];
    const float* x   = (const float*)d_in[1];
    const float* f_y = (const float*)d_in[2];
    const int*   nbr = (const int*)d_in[3];
    // d_in[4] = neighbors_row_splits (uniform arange*32) -- unused
    const float* wts = (const float*)d_in[5];
    const float* W0  = (const float*)d_in[6];
    const float* b0  = (const float*)d_in[7];
    const float* W1  = (const float*)d_in[8];
    const float* b1  = (const float*)d_in[9];
    const float* W2  = (const float*)d_in[10];
    const float* b2  = (const float*)d_in[11];
    unsigned short* wp = (unsigned short*)d_ws;   // 180224 B of packed bf16 fragments
    float* out = (float*)d_out;

    pack_w<<<dim3(44), dim3(256), 0, stream>>>(W0, W1, W2, wp);
    gno_fused<<<dim3(NEDGES / TM), dim3(256), 0, stream>>>(
        y, x, f_y, nbr, wts, b0, b1, b2, wp, out);
}

// Round 3
// 298.000 us; speedup vs baseline: 1.0215x; 1.0215x over previous
//
#include <hip/hip_runtime.h>
#include <hip/hip_bf16.h>
#include <stdint.h>

#define NPTS 32768
#define KNBR 32
#define NEDGES (NPTS * KNBR)
#define TM 64           // edges per block (= 2 output rows)
#define AGG_STRIDE 40   // bf16 elems per agg row (80 B, 16B aligned)
#define H_STRIDE 264    // bf16 elems per h row (528 B, 16B aligned)

typedef __attribute__((ext_vector_type(8))) short short8;
typedef __attribute__((ext_vector_type(4))) float f32x4;
typedef __attribute__((ext_vector_type(4))) unsigned int u32x4;
typedef __attribute__((ext_vector_type(2))) unsigned int u32x2;

// round-to-nearest-even f32 -> bf16
__device__ __forceinline__ unsigned short f2bf(float f) {
    unsigned int u = __float_as_uint(f);
    unsigned int r = (u + 0x7FFFu + ((u >> 16) & 1u)) >> 16;
    return (unsigned short)r;
}

__device__ __forceinline__ unsigned int pack2bf(float a, float b) {
    return (unsigned int)f2bf(a) | ((unsigned int)f2bf(b) << 16);
}

// pack 4 floats -> 4 bf16 and store as one b64
__device__ __forceinline__ void store_h4(unsigned short* p, float a, float b, float c, float d) {
    u32x2 v;
    v.x = pack2bf(a, b);
    v.y = pack2bf(c, d);
    *reinterpret_cast<u32x2*>(p) = v;
}

// jax.nn.gelu approximate=True via sigmoid identity:
// gelu(x) = x / (1 + exp2(-2.30220824 * x*(1 + 0.044715 x^2)))
__device__ __forceinline__ float gelu_tanh(float x) {
    float x2 = x * x;
    float u = fmaf(-0.102942496f, x2, -2.30220824f);  // -2.302208*(1+0.044715 x^2)
    float e = __builtin_amdgcn_exp2f(x * u);
    return x * __builtin_amdgcn_rcpf(1.0f + e);
}

// ---------------- weight packing into MFMA fragment layout (bf16) ----------------
// Fragment (kstep s, ntile nt): lane l supplies W[k0+j][nt*16 + (l&15)],
// k0 = s*32 + (l>>4)*8, j=0..7. Used as the A operand (=> effective A = W^T).
__global__ void pack_w(const float* __restrict__ W0, const float* __restrict__ W1,
                       const float* __restrict__ W2, unsigned short* __restrict__ wp) {
    int tid = blockIdx.x * blockDim.x + threadIdx.x;
    if (tid >= 11264) return;
    unsigned short v[8];
    int l = tid & 63;
    if (tid < 1024) {                 // W0: 6x256, K padded to 32 with zeros
        int nt = tid >> 6;
        int n = nt * 16 + (l & 15);
        int k0 = (l >> 4) << 3;
        #pragma unroll
        for (int j = 0; j < 8; ++j) {
            int k = k0 + j;
            v[j] = f2bf(k < 6 ? W0[k * 256 + n] : 0.0f);
        }
    } else if (tid < 9216) {          // W1: 256x256
        int q = tid - 1024;
        int nt = (q >> 6) & 15;
        int s = q >> 10;
        int n = nt * 16 + (l & 15);
        int k0 = s * 32 + ((l >> 4) << 3);
        #pragma unroll
        for (int j = 0; j < 8; ++j) v[j] = f2bf(W1[(k0 + j) * 256 + n]);
    } else {                          // W2: 256x64
        int q = tid - 9216;
        int nt = (q >> 6) & 3;
        int s = q >> 8;
        int n = nt * 16 + (l & 15);
        int k0 = s * 32 + ((l >> 4) << 3);
        #pragma unroll
        for (int j = 0; j < 8; ++j) v[j] = f2bf(W2[(k0 + j) * 64 + n]);
    }
    unsigned short* o = &wp[tid * 8];
    #pragma unroll
    for (int j = 0; j < 8; ++j) o[j] = v[j];
}

// ---------------- fused GNO kernel (transposed GEMMs: D = W^T * act^T) -------------
// Output fragment: col(lane&15) = edge row, row(lg*4+i) = channel -> 4 consecutive
// channels per lane => vectorized h-stores, float4 bias/f_y loads.
__global__ __launch_bounds__(256, 4)
void gno_fused(const float* __restrict__ y, const float* __restrict__ x,
               const float* __restrict__ f_y, const int* __restrict__ nbr,
               const float* __restrict__ wts,
               const float* __restrict__ b0, const float* __restrict__ b1,
               const float* __restrict__ b2,
               const unsigned short* __restrict__ wp,
               float* __restrict__ out) {
    __shared__ __align__(16) unsigned short agg_lds[TM * AGG_STRIDE];  // 5 KB
    __shared__ __align__(16) unsigned short h_lds[TM * H_STRIDE];      // 33 KB

    const int b = blockIdx.x;
    const int tid = threadIdx.x;
    const int l = tid & 63;
    const int w = tid >> 6;          // wave 0..3
    const int lg = l >> 4;           // lane group 0..3
    const int ln = l & 15;
    const int ebase = b * TM;

    // ---- stage agg = [y[nbr[e]] (3), x[e>>5] (3), 0...] as bf16, K padded to 32
    if (tid < TM) {
        int e = ebase + tid;
        int j = nbr[e];
        int i = e >> 5;              // uniform CSR: row_splits = arange*32
        const float* yr = &y[j * 3];
        const float* xr = &x[i * 3];
        u32x4 q0;
        q0.x = pack2bf(yr[0], yr[1]);
        q0.y = pack2bf(yr[2], xr[0]);
        q0.z = pack2bf(xr[1], xr[2]);
        q0.w = 0u;
        u32x4 z = {0u, 0u, 0u, 0u};
        unsigned short* row = &agg_lds[tid * AGG_STRIDE];
        *(u32x4*)(row +  0) = q0;
        *(u32x4*)(row +  8) = z;
        *(u32x4*)(row + 16) = z;
        *(u32x4*)(row + 24) = z;
    }
    __syncthreads();

    // ---- GEMM1: h0^T = W0^T @ agg^T, gelu  (wave w owns channels [64w, 64w+64))
    {
        short8 aw[4];
        f32x4 b0v[4];
        #pragma unroll
        for (int n = 0; n < 4; ++n) {
            int nt = 4 * w + n;
            aw[n] = *(const short8*)&wp[(nt * 64 + l) * 8];
            b0v[n] = *(const f32x4*)&b0[nt * 16 + lg * 4];
        }
        f32x4 zero = {0.f, 0.f, 0.f, 0.f};
        #pragma unroll
        for (int mt = 0; mt < 4; ++mt) {
            short8 ag = *(const short8*)&agg_lds[(mt * 16 + ln) * AGG_STRIDE + lg * 8];
            #pragma unroll
            for (int n = 0; n < 4; ++n) {
                f32x4 c = __builtin_amdgcn_mfma_f32_16x16x32_bf16(aw[n], ag, zero, 0, 0, 0);
                float g0 = gelu_tanh(c[0] + b0v[n][0]);
                float g1 = gelu_tanh(c[1] + b0v[n][1]);
                float g2 = gelu_tanh(c[2] + b0v[n][2]);
                float g3 = gelu_tanh(c[3] + b0v[n][3]);
                store_h4(&h_lds[(mt * 16 + ln) * H_STRIDE + (4 * w + n) * 16 + lg * 4],
                         g0, g1, g2, g3);
            }
        }
    }
    __syncthreads();

    // ---- GEMM2: h1^T = W1^T @ h0^T, K=256
    f32x4 acc[4][4];
    #pragma unroll
    for (int mt = 0; mt < 4; ++mt)
        #pragma unroll
        for (int n = 0; n < 4; ++n)
            acc[mt][n] = (f32x4){0.f, 0.f, 0.f, 0.f};

    #pragma unroll
    for (int s = 0; s < 8; ++s) {
        short8 aw[4];
        #pragma unroll
        for (int n = 0; n < 4; ++n)
            aw[n] = *(const short8*)&wp[(1024 + (s * 16 + 4 * w + n) * 64 + l) * 8];
        #pragma unroll
        for (int mt = 0; mt < 4; ++mt) {
            short8 hb = *(const short8*)&h_lds[(mt * 16 + ln) * H_STRIDE + s * 32 + lg * 8];
            #pragma unroll
            for (int n = 0; n < 4; ++n)
                acc[mt][n] = __builtin_amdgcn_mfma_f32_16x16x32_bf16(aw[n], hb, acc[mt][n], 0, 0, 0);
        }
    }
    __syncthreads();   // all waves done READING h0 before overwriting with h1

    {
        f32x4 b1v[4];
        #pragma unroll
        for (int n = 0; n < 4; ++n) b1v[n] = *(const f32x4*)&b1[(4 * w + n) * 16 + lg * 4];
        #pragma unroll
        for (int mt = 0; mt < 4; ++mt) {
            #pragma unroll
            for (int n = 0; n < 4; ++n) {
                float g0 = gelu_tanh(acc[mt][n][0] + b1v[n][0]);
                float g1 = gelu_tanh(acc[mt][n][1] + b1v[n][1]);
                float g2 = gelu_tanh(acc[mt][n][2] + b1v[n][2]);
                float g3 = gelu_tanh(acc[mt][n][3] + b1v[n][3]);
                store_h4(&h_lds[(mt * 16 + ln) * H_STRIDE + (4 * w + n) * 16 + lg * 4],
                         g0, g1, g2, g3);
            }
        }
    }
    __syncthreads();

    // ---- GEMM3: rep^T = W2^T @ h1^T  (wave w owns channels [16w, 16w+16))
    f32x4 acc3[4];
    #pragma unroll
    for (int mt = 0; mt < 4; ++mt) acc3[mt] = (f32x4){0.f, 0.f, 0.f, 0.f};

    #pragma unroll
    for (int s = 0; s < 8; ++s) {
        short8 aw = *(const short8*)&wp[(9216 + (s * 4 + w) * 64 + l) * 8];
        #pragma unroll
        for (int mt = 0; mt < 4; ++mt) {
            short8 hb = *(const short8*)&h_lds[(mt * 16 + ln) * H_STRIDE + s * 32 + lg * 8];
            acc3[mt] = __builtin_amdgcn_mfma_f32_16x16x32_bf16(aw, hb, acc3[mt], 0, 0, 0);
        }
    }

    // ---- epilogue: (rep + b2) * f_y[nbr] * wts, segment-sum over 32 edges/row
    {
        f32x4 b2v = *(const f32x4*)&b2[w * 16 + lg * 4];
        f32x4 seg[2];
        seg[0] = (f32x4){0.f, 0.f, 0.f, 0.f};
        seg[1] = (f32x4){0.f, 0.f, 0.f, 0.f};
        #pragma unroll
        for (int mt = 0; mt < 4; ++mt) {
            int e = ebase + mt * 16 + ln;
            int j = nbr[e];
            f32x4 fy = *(const f32x4*)&f_y[j * 64 + w * 16 + lg * 4];
            float wt = wts[e];
            f32x4 v;
            #pragma unroll
            for (int i = 0; i < 4; ++i)
                v[i] = (acc3[mt][i] + b2v[i]) * fy[i] * wt;
            seg[mt >> 1] += v;
        }
        #pragma unroll
        for (int g = 0; g < 2; ++g) {
            f32x4 v = seg[g];
            #pragma unroll
            for (int d = 1; d <= 8; d <<= 1) {
                #pragma unroll
                for (int i = 0; i < 4; ++i)
                    v[i] += __shfl_xor(v[i], d, 64);
            }
            if (ln == 0)
                *(f32x4*)&out[(b * 2 + g) * 64 + w * 16 + lg * 4] = v;
        }
    }
}

extern "C" void kernel_launch(void* const* d_in, const int* in_sizes, int n_in,
                              void* d_out, int out_size, void* d_ws, size_t ws_size,
                              hipStream_t stream) {
    const float* y   = (const float*)d_in[0];
    const float* x   = (const float*)d_in[1];
    const float* f_y = (const float*)d_in[2];
    const int*   nbr = (const int*)d_in[3];
    // d_in[4] = neighbors_row_splits (uniform arange*32) -- unused
    const float* wts = (const float*)d_in[5];
    const float* W0  = (const float*)d_in[6];
    const float* b0  = (const float*)d_in[7];
    const float* W1  = (const float*)d_in[8];
    const float* b1  = (const float*)d_in[9];
    const float* W2  = (const float*)d_in[10];
    const float* b2  = (const float*)d_in[11];
    unsigned short* wp = (unsigned short*)d_ws;   // 180224 B of packed bf16 fragments
    float* out = (float*)d_out;

    pack_w<<<dim3(44), dim3(256), 0, stream>>>(W0, W1, W2, wp);
    gno_fused<<<dim3(NEDGES / TM), dim3(256), 0, stream>>>(
        y, x, f_y, nbr, wts, b0, b1, b2, wp, out);
}

// Round 4
// 297.113 us; speedup vs baseline: 1.0246x; 1.0030x over previous
//
#include <hip/hip_runtime.h>
#include <hip/hip_bf16.h>
#include <stdint.h>

#define NPTS 32768
#define KNBR 32
#define NEDGES (NPTS * KNBR)
#define TM 64           // edges per block (= 2 output rows)
#define AGG_STRIDE 40   // bf16 elems per agg row (80 B, 16B aligned)
#define H_STRIDE 264    // bf16 elems per h row (528 B, 16B aligned)

typedef __attribute__((ext_vector_type(8))) short short8;
typedef __attribute__((ext_vector_type(4))) float f32x4;
typedef __attribute__((ext_vector_type(4))) unsigned int u32x4;
typedef __attribute__((ext_vector_type(2))) unsigned int u32x2;

// round-to-nearest-even f32 -> bf16
__device__ __forceinline__ unsigned short f2bf(float f) {
    unsigned int u = __float_as_uint(f);
    unsigned int r = (u + 0x7FFFu + ((u >> 16) & 1u)) >> 16;
    return (unsigned short)r;
}

__device__ __forceinline__ unsigned int pack2bf(float a, float b) {
    return (unsigned int)f2bf(a) | ((unsigned int)f2bf(b) << 16);
}

// pack 4 floats -> 4 bf16 and store as one b64
__device__ __forceinline__ void store_h4(unsigned short* p, float a, float b, float c, float d) {
    u32x2 v;
    v.x = pack2bf(a, b);
    v.y = pack2bf(c, d);
    *reinterpret_cast<u32x2*>(p) = v;
}

// jax.nn.gelu approximate=True via sigmoid identity:
// gelu(x) = x / (1 + exp2(-2.30220824 * x*(1 + 0.044715 x^2)))
__device__ __forceinline__ float gelu_tanh(float x) {
    float x2 = x * x;
    float u = fmaf(-0.102942496f, x2, -2.30220824f);  // -2.302208*(1+0.044715 x^2)
    float e = __builtin_amdgcn_exp2f(x * u);
    return x * __builtin_amdgcn_rcpf(1.0f + e);
}

// ---------------- weight packing into MFMA fragment layout (bf16) ----------------
// Fragment (kstep s, ntile nt): lane l supplies W[k0+j][nt*16 + (l&15)],
// k0 = s*32 + (l>>4)*8, j=0..7. Used as the A operand (=> effective A = W^T).
__global__ void pack_w(const float* __restrict__ W0, const float* __restrict__ W1,
                       const float* __restrict__ W2, unsigned short* __restrict__ wp) {
    int tid = blockIdx.x * blockDim.x + threadIdx.x;
    if (tid >= 11264) return;
    unsigned short v[8];
    int l = tid & 63;
    if (tid < 1024) {                 // W0: 6x256, K padded to 32 with zeros
        int nt = tid >> 6;
        int n = nt * 16 + (l & 15);
        int k0 = (l >> 4) << 3;
        #pragma unroll
        for (int j = 0; j < 8; ++j) {
            int k = k0 + j;
            v[j] = f2bf(k < 6 ? W0[k * 256 + n] : 0.0f);
        }
    } else if (tid < 9216) {          // W1: 256x256
        int q = tid - 1024;
        int nt = (q >> 6) & 15;
        int s = q >> 10;
        int n = nt * 16 + (l & 15);
        int k0 = s * 32 + ((l >> 4) << 3);
        #pragma unroll
        for (int j = 0; j < 8; ++j) v[j] = f2bf(W1[(k0 + j) * 256 + n]);
    } else {                          // W2: 256x64
        int q = tid - 9216;
        int nt = (q >> 6) & 3;
        int s = q >> 8;
        int n = nt * 16 + (l & 15);
        int k0 = s * 32 + ((l >> 4) << 3);
        #pragma unroll
        for (int j = 0; j < 8; ++j) v[j] = f2bf(W2[(k0 + j) * 64 + n]);
    }
    unsigned short* o = &wp[tid * 8];
    #pragma unroll
    for (int j = 0; j < 8; ++j) o[j] = v[j];
}

// ---------------- fused GNO kernel (transposed GEMMs: D = W^T * act^T) -------------
// Output fragment: col(lane&15) = edge row, row(lg*4+i) = channel -> 4 consecutive
// channels per lane => vectorized h-stores, float4 bias/f_y loads.
// launch_bounds (256,3): 512/3 ~= 170 unified regs/wave = 64 AGPR acc + ~106 VGPR
// working set. (256,4) = 128 budget spilled (R2: WRITE_SIZE 73.5 MB of scratch).
__global__ __launch_bounds__(256, 3)
void gno_fused(const float* __restrict__ y, const float* __restrict__ x,
               const float* __restrict__ f_y, const int* __restrict__ nbr,
               const float* __restrict__ wts,
               const float* __restrict__ b0, const float* __restrict__ b1,
               const float* __restrict__ b2,
               const unsigned short* __restrict__ wp,
               float* __restrict__ out) {
    __shared__ __align__(16) unsigned short agg_lds[TM * AGG_STRIDE];  // 5 KB
    __shared__ __align__(16) unsigned short h_lds[TM * H_STRIDE];      // 33 KB

    const int b = blockIdx.x;
    const int tid = threadIdx.x;
    const int l = tid & 63;
    const int w = tid >> 6;          // wave 0..3
    const int lg = l >> 4;           // lane group 0..3
    const int ln = l & 15;
    const int ebase = b * TM;

    // ---- stage agg = [y[nbr[e]] (3), x[e>>5] (3), 0...] as bf16, K padded to 32
    if (tid < TM) {
        int e = ebase + tid;
        int j = nbr[e];
        int i = e >> 5;              // uniform CSR: row_splits = arange*32
        const float* yr = &y[j * 3];
        const float* xr = &x[i * 3];
        u32x4 q0;
        q0.x = pack2bf(yr[0], yr[1]);
        q0.y = pack2bf(yr[2], xr[0]);
        q0.z = pack2bf(xr[1], xr[2]);
        q0.w = 0u;
        u32x4 z = {0u, 0u, 0u, 0u};
        unsigned short* row = &agg_lds[tid * AGG_STRIDE];
        *(u32x4*)(row +  0) = q0;
        *(u32x4*)(row +  8) = z;
        *(u32x4*)(row + 16) = z;
        *(u32x4*)(row + 24) = z;
    }
    __syncthreads();

    // ---- GEMM1: h0^T = W0^T @ agg^T, gelu  (wave w owns channels [64w, 64w+64))
    {
        short8 aw[4];
        f32x4 b0v[4];
        #pragma unroll
        for (int n = 0; n < 4; ++n) {
            int nt = 4 * w + n;
            aw[n] = *(const short8*)&wp[(nt * 64 + l) * 8];
            b0v[n] = *(const f32x4*)&b0[nt * 16 + lg * 4];
        }
        f32x4 zero = {0.f, 0.f, 0.f, 0.f};
        #pragma unroll
        for (int mt = 0; mt < 4; ++mt) {
            short8 ag = *(const short8*)&agg_lds[(mt * 16 + ln) * AGG_STRIDE + lg * 8];
            #pragma unroll
            for (int n = 0; n < 4; ++n) {
                f32x4 c = __builtin_amdgcn_mfma_f32_16x16x32_bf16(aw[n], ag, zero, 0, 0, 0);
                float g0 = gelu_tanh(c[0] + b0v[n][0]);
                float g1 = gelu_tanh(c[1] + b0v[n][1]);
                float g2 = gelu_tanh(c[2] + b0v[n][2]);
                float g3 = gelu_tanh(c[3] + b0v[n][3]);
                store_h4(&h_lds[(mt * 16 + ln) * H_STRIDE + (4 * w + n) * 16 + lg * 4],
                         g0, g1, g2, g3);
            }
        }
    }
    __syncthreads();

    // ---- GEMM2: h1^T = W1^T @ h0^T, K=256
    f32x4 acc[4][4];
    #pragma unroll
    for (int mt = 0; mt < 4; ++mt)
        #pragma unroll
        for (int n = 0; n < 4; ++n)
            acc[mt][n] = (f32x4){0.f, 0.f, 0.f, 0.f};

    #pragma unroll
    for (int s = 0; s < 8; ++s) {
        short8 aw[4];
        #pragma unroll
        for (int n = 0; n < 4; ++n)
            aw[n] = *(const short8*)&wp[(1024 + (s * 16 + 4 * w + n) * 64 + l) * 8];
        #pragma unroll
        for (int mt = 0; mt < 4; ++mt) {
            short8 hb = *(const short8*)&h_lds[(mt * 16 + ln) * H_STRIDE + s * 32 + lg * 8];
            #pragma unroll
            for (int n = 0; n < 4; ++n)
                acc[mt][n] = __builtin_amdgcn_mfma_f32_16x16x32_bf16(aw[n], hb, acc[mt][n], 0, 0, 0);
        }
    }
    __syncthreads();   // all waves done READING h0 before overwriting with h1

    {
        f32x4 b1v[4];
        #pragma unroll
        for (int n = 0; n < 4; ++n) b1v[n] = *(const f32x4*)&b1[(4 * w + n) * 16 + lg * 4];
        #pragma unroll
        for (int mt = 0; mt < 4; ++mt) {
            #pragma unroll
            for (int n = 0; n < 4; ++n) {
                float g0 = gelu_tanh(acc[mt][n][0] + b1v[n][0]);
                float g1 = gelu_tanh(acc[mt][n][1] + b1v[n][1]);
                float g2 = gelu_tanh(acc[mt][n][2] + b1v[n][2]);
                float g3 = gelu_tanh(acc[mt][n][3] + b1v[n][3]);
                store_h4(&h_lds[(mt * 16 + ln) * H_STRIDE + (4 * w + n) * 16 + lg * 4],
                         g0, g1, g2, g3);
            }
        }
    }
    __syncthreads();

    // ---- GEMM3: rep^T = W2^T @ h1^T  (wave w owns channels [16w, 16w+16))
    f32x4 acc3[4];
    #pragma unroll
    for (int mt = 0; mt < 4; ++mt) acc3[mt] = (f32x4){0.f, 0.f, 0.f, 0.f};

    #pragma unroll
    for (int s = 0; s < 8; ++s) {
        short8 aw = *(const short8*)&wp[(9216 + (s * 4 + w) * 64 + l) * 8];
        #pragma unroll
        for (int mt = 0; mt < 4; ++mt) {
            short8 hb = *(const short8*)&h_lds[(mt * 16 + ln) * H_STRIDE + s * 32 + lg * 8];
            acc3[mt] = __builtin_amdgcn_mfma_f32_16x16x32_bf16(aw, hb, acc3[mt], 0, 0, 0);
        }
    }

    // ---- epilogue: (rep + b2) * f_y[nbr] * wts, segment-sum over 32 edges/row
    {
        f32x4 b2v = *(const f32x4*)&b2[w * 16 + lg * 4];
        f32x4 seg[2];
        seg[0] = (f32x4){0.f, 0.f, 0.f, 0.f};
        seg[1] = (f32x4){0.f, 0.f, 0.f, 0.f};
        #pragma unroll
        for (int mt = 0; mt < 4; ++mt) {
            int e = ebase + mt * 16 + ln;
            int j = nbr[e];
            f32x4 fy = *(const f32x4*)&f_y[j * 64 + w * 16 + lg * 4];
            float wt = wts[e];
            f32x4 v;
            #pragma unroll
            for (int i = 0; i < 4; ++i)
                v[i] = (acc3[mt][i] + b2v[i]) * fy[i] * wt;
            seg[mt >> 1] += v;
        }
        #pragma unroll
        for (int g = 0; g < 2; ++g) {
            f32x4 v = seg[g];
            #pragma unroll
            for (int d = 1; d <= 8; d <<= 1) {
                #pragma unroll
                for (int i = 0; i < 4; ++i)
                    v[i] += __shfl_xor(v[i], d, 64);
            }
            if (ln == 0)
                *(f32x4*)&out[(b * 2 + g) * 64 + w * 16 + lg * 4] = v;
        }
    }
}

extern "C" void kernel_launch(void* const* d_in, const int* in_sizes, int n_in,
                              void* d_out, int out_size, void* d_ws, size_t ws_size,
                              hipStream_t stream) {
    const float* y   = (const float*)d_in[0];
    const float* x   = (const float*)d_in[1];
    const float* f_y = (const float*)d_in[2];
    const int*   nbr = (const int*)d_in[3];
    // d_in[4] = neighbors_row_splits (uniform arange*32) -- unused
    const float* wts = (const float*)d_in[5];
    const float* W0  = (const float*)d_in[6];
    const float* b0  = (const float*)d_in[7];
    const float* W1  = (const float*)d_in[8];
    const float* b1  = (const float*)d_in[9];
    const float* W2  = (const float*)d_in[10];
    const float* b2  = (const float*)d_in[11];
    unsigned short* wp = (unsigned short*)d_ws;   // 180224 B of packed bf16 fragments
    float* out = (float*)d_out;

    pack_w<<<dim3(44), dim3(256), 0, stream>>>(W0, W1, W2, wp);
    gno_fused<<<dim3(NEDGES / TM), dim3(256), 0, stream>>>(
        y, x, f_y, nbr, wts, b0, b1, b2, wp, out);
}

// Round 5
// 293.858 us; speedup vs baseline: 1.0359x; 1.0111x over previous
//
#include <hip/hip_runtime.h>
#include <hip/hip_bf16.h>
#include <stdint.h>

#define NPTS 32768
#define KNBR 32
#define NEDGES (NPTS * KNBR)
#define TM 64           // edges per block (= 2 output rows)
#define AGG_STRIDE 40   // bf16 elems per agg row (80 B, 16B aligned)
#define H_STRIDE 264    // bf16 elems per h row (528 B, 16B aligned)

typedef __attribute__((ext_vector_type(8))) short short8;
typedef __attribute__((ext_vector_type(4))) float f32x4;
typedef __attribute__((ext_vector_type(4))) unsigned int u32x4;
typedef __attribute__((ext_vector_type(2))) unsigned int u32x2;

// round-to-nearest-even f32 -> bf16 (one-time pack kernel only)
__device__ __forceinline__ unsigned short f2bf(float f) {
    unsigned int u = __float_as_uint(f);
    unsigned int r = (u + 0x7FFFu + ((u >> 16) & 1u)) >> 16;
    return (unsigned short)r;
}

// gfx950 packed f32->bf16 (RNE), single instruction
__device__ __forceinline__ unsigned int cvt_pk_bf16(float lo, float hi) {
    unsigned int r;
    asm("v_cvt_pk_bf16_f32 %0, %1, %2" : "=v"(r) : "v"(lo), "v"(hi));
    return r;
}

// pack 4 floats -> 4 bf16 and store as one b64
__device__ __forceinline__ void store_h4(unsigned short* p, float a, float b, float c, float d) {
    u32x2 v;
    v.x = cvt_pk_bf16(a, b);
    v.y = cvt_pk_bf16(c, d);
    *reinterpret_cast<u32x2*>(p) = v;
}

// jax.nn.gelu approximate=True via sigmoid identity:
// gelu(x) = x / (1 + exp2(-2.30220824 * x*(1 + 0.044715 x^2)))
__device__ __forceinline__ float gelu_tanh(float x) {
    float x2 = x * x;
    float u = fmaf(-0.102942496f, x2, -2.30220824f);  // -2.302208*(1+0.044715 x^2)
    float e = __builtin_amdgcn_exp2f(x * u);
    return x * __builtin_amdgcn_rcpf(1.0f + e);
}

// ---------------- weight packing into MFMA fragment layout (bf16) ----------------
// Fragment (kstep s, ntile nt): lane l supplies W[k0+j][nt*16 + (l&15)],
// k0 = s*32 + (l>>4)*8, j=0..7. Used as the A operand (=> effective A = W^T).
__global__ void pack_w(const float* __restrict__ W0, const float* __restrict__ W1,
                       const float* __restrict__ W2, unsigned short* __restrict__ wp) {
    int tid = blockIdx.x * blockDim.x + threadIdx.x;
    if (tid >= 11264) return;
    unsigned short v[8];
    int l = tid & 63;
    if (tid < 1024) {                 // W0: 6x256, K padded to 32 with zeros
        int nt = tid >> 6;
        int n = nt * 16 + (l & 15);
        int k0 = (l >> 4) << 3;
        #pragma unroll
        for (int j = 0; j < 8; ++j) {
            int k = k0 + j;
            v[j] = f2bf(k < 6 ? W0[k * 256 + n] : 0.0f);
        }
    } else if (tid < 9216) {          // W1: 256x256
        int q = tid - 1024;
        int nt = (q >> 6) & 15;
        int s = q >> 10;
        int n = nt * 16 + (l & 15);
        int k0 = s * 32 + ((l >> 4) << 3);
        #pragma unroll
        for (int j = 0; j < 8; ++j) v[j] = f2bf(W1[(k0 + j) * 256 + n]);
    } else {                          // W2: 256x64
        int q = tid - 9216;
        int nt = (q >> 6) & 3;
        int s = q >> 8;
        int n = nt * 16 + (l & 15);
        int k0 = s * 32 + ((l >> 4) << 3);
        #pragma unroll
        for (int j = 0; j < 8; ++j) v[j] = f2bf(W2[(k0 + j) * 64 + n]);
    }
    unsigned short* o = &wp[tid * 8];
    #pragma unroll
    for (int j = 0; j < 8; ++j) o[j] = v[j];
}

// ---------------- fused GNO kernel (transposed GEMMs: D = W^T * act^T) -------------
// 2x2 wave tiling: wave (wm = w&1, wn = w>>1) owns edge tiles {2wm, 2wm+1} (32 edges)
// x channel half [128*wn, 128*wn+128). Halves redundant LDS activation reads vs 1x4.
__global__ __launch_bounds__(256, 3)
void gno_fused(const float* __restrict__ y, const float* __restrict__ x,
               const float* __restrict__ f_y, const int* __restrict__ nbr,
               const float* __restrict__ wts,
               const float* __restrict__ b0, const float* __restrict__ b1,
               const float* __restrict__ b2,
               const unsigned short* __restrict__ wp,
               float* __restrict__ out) {
    __shared__ __align__(16) unsigned short agg_lds[TM * AGG_STRIDE];  // 5 KB
    __shared__ __align__(16) unsigned short h_lds[TM * H_STRIDE];      // 33 KB

    const int b = blockIdx.x;
    const int tid = threadIdx.x;
    const int l = tid & 63;
    const int w = tid >> 6;          // wave 0..3
    const int wm = w & 1;            // edge-tile half
    const int wn = w >> 1;           // channel half
    const int lg = l >> 4;           // lane group 0..3
    const int ln = l & 15;
    const int ebase = b * TM;

    // ---- stage agg = [y[nbr[e]] (3), x[e>>5] (3), 0...] as bf16, K padded to 32
    if (tid < TM) {
        int e = ebase + tid;
        int j = nbr[e];
        int i = e >> 5;              // uniform CSR: row_splits = arange*32
        const float* yr = &y[j * 3];
        const float* xr = &x[i * 3];
        u32x4 q0;
        q0.x = cvt_pk_bf16(yr[0], yr[1]);
        q0.y = cvt_pk_bf16(yr[2], xr[0]);
        q0.z = cvt_pk_bf16(xr[1], xr[2]);
        q0.w = 0u;
        u32x4 z = {0u, 0u, 0u, 0u};
        unsigned short* row = &agg_lds[tid * AGG_STRIDE];
        *(u32x4*)(row +  0) = q0;
        *(u32x4*)(row +  8) = z;
        *(u32x4*)(row + 16) = z;
        *(u32x4*)(row + 24) = z;
    }
    __syncthreads();

    // ---- GEMM1: h0^T = W0^T @ agg^T, gelu; wave does 2 edge tiles x 8 ntiles
    {
        short8 ag[2];
        #pragma unroll
        for (int m = 0; m < 2; ++m)
            ag[m] = *(const short8*)&agg_lds[((2 * wm + m) * 16 + ln) * AGG_STRIDE + lg * 8];
        f32x4 zero = {0.f, 0.f, 0.f, 0.f};
        #pragma unroll
        for (int n = 0; n < 8; ++n) {
            int nt = 8 * wn + n;
            short8 aw = *(const short8*)&wp[(nt * 64 + l) * 8];
            f32x4 b0v = *(const f32x4*)&b0[nt * 16 + lg * 4];
            #pragma unroll
            for (int m = 0; m < 2; ++m) {
                int mt = 2 * wm + m;
                f32x4 c = __builtin_amdgcn_mfma_f32_16x16x32_bf16(aw, ag[m], zero, 0, 0, 0);
                float g0 = gelu_tanh(c[0] + b0v[0]);
                float g1 = gelu_tanh(c[1] + b0v[1]);
                float g2 = gelu_tanh(c[2] + b0v[2]);
                float g3 = gelu_tanh(c[3] + b0v[3]);
                store_h4(&h_lds[(mt * 16 + ln) * H_STRIDE + nt * 16 + lg * 4],
                         g0, g1, g2, g3);
            }
        }
    }
    __syncthreads();

    // ---- GEMM2: h1^T = W1^T @ h0^T, K=256; acc[2 edge tiles][8 ntiles]
    f32x4 acc[2][8];
    #pragma unroll
    for (int m = 0; m < 2; ++m)
        #pragma unroll
        for (int n = 0; n < 8; ++n)
            acc[m][n] = (f32x4){0.f, 0.f, 0.f, 0.f};

    #pragma unroll
    for (int s = 0; s < 8; ++s) {
        short8 hb[2];
        #pragma unroll
        for (int m = 0; m < 2; ++m)
            hb[m] = *(const short8*)&h_lds[((2 * wm + m) * 16 + ln) * H_STRIDE + s * 32 + lg * 8];
        #pragma unroll
        for (int n = 0; n < 8; ++n) {
            short8 aw = *(const short8*)&wp[(1024 + (s * 16 + 8 * wn + n) * 64 + l) * 8];
            #pragma unroll
            for (int m = 0; m < 2; ++m)
                acc[m][n] = __builtin_amdgcn_mfma_f32_16x16x32_bf16(aw, hb[m], acc[m][n], 0, 0, 0);
        }
    }
    __syncthreads();   // all waves done READING h0 before overwriting with h1

    {
        #pragma unroll
        for (int n = 0; n < 8; ++n) {
            int nt = 8 * wn + n;
            f32x4 b1v = *(const f32x4*)&b1[nt * 16 + lg * 4];
            #pragma unroll
            for (int m = 0; m < 2; ++m) {
                int mt = 2 * wm + m;
                float g0 = gelu_tanh(acc[m][n][0] + b1v[0]);
                float g1 = gelu_tanh(acc[m][n][1] + b1v[1]);
                float g2 = gelu_tanh(acc[m][n][2] + b1v[2]);
                float g3 = gelu_tanh(acc[m][n][3] + b1v[3]);
                store_h4(&h_lds[(mt * 16 + ln) * H_STRIDE + nt * 16 + lg * 4],
                         g0, g1, g2, g3);
            }
        }
    }
    __syncthreads();

    // ---- GEMM3: rep^T = W2^T @ h1^T; wave does 2 edge tiles x 2 ntiles (32 ch)
    f32x4 acc3[2][2];
    #pragma unroll
    for (int m = 0; m < 2; ++m)
        #pragma unroll
        for (int jj = 0; jj < 2; ++jj)
            acc3[m][jj] = (f32x4){0.f, 0.f, 0.f, 0.f};

    #pragma unroll
    for (int s = 0; s < 8; ++s) {
        short8 hb[2];
        #pragma unroll
        for (int m = 0; m < 2; ++m)
            hb[m] = *(const short8*)&h_lds[((2 * wm + m) * 16 + ln) * H_STRIDE + s * 32 + lg * 8];
        #pragma unroll
        for (int jj = 0; jj < 2; ++jj) {
            short8 aw = *(const short8*)&wp[(9216 + (s * 4 + 2 * wn + jj) * 64 + l) * 8];
            #pragma unroll
            for (int m = 0; m < 2; ++m)
                acc3[m][jj] = __builtin_amdgcn_mfma_f32_16x16x32_bf16(aw, hb[m], acc3[m][jj], 0, 0, 0);
        }
    }

    // ---- epilogue: (rep + b2) * f_y[nbr] * wts, segment-sum over 32 edges/row
    // wave (wm, wn) owns out row (2b + wm), channels [32*wn, 32*wn+32)
    {
        f32x4 seg[2];
        seg[0] = (f32x4){0.f, 0.f, 0.f, 0.f};
        seg[1] = (f32x4){0.f, 0.f, 0.f, 0.f};
        #pragma unroll
        for (int m = 0; m < 2; ++m) {
            int e = ebase + (2 * wm + m) * 16 + ln;
            int j = nbr[e];
            float wt = wts[e];
            #pragma unroll
            for (int jj = 0; jj < 2; ++jj) {
                int ch = (2 * wn + jj) * 16 + lg * 4;
                f32x4 fy = *(const f32x4*)&f_y[j * 64 + ch];
                f32x4 b2v = *(const f32x4*)&b2[ch];
                f32x4 v;
                #pragma unroll
                for (int i = 0; i < 4; ++i)
                    v[i] = (acc3[m][jj][i] + b2v[i]) * fy[i] * wt;
                seg[jj] += v;
            }
        }
        #pragma unroll
        for (int jj = 0; jj < 2; ++jj) {
            f32x4 v = seg[jj];
            #pragma unroll
            for (int d = 1; d <= 8; d <<= 1) {
                #pragma unroll
                for (int i = 0; i < 4; ++i)
                    v[i] += __shfl_xor(v[i], d, 64);
            }
            if (ln == 0)
                *(f32x4*)&out[(2 * b + wm) * 64 + (2 * wn + jj) * 16 + lg * 4] = v;
        }
    }
}

extern "C" void kernel_launch(void* const* d_in, const int* in_sizes, int n_in,
                              void* d_out, int out_size, void* d_ws, size_t ws_size,
                              hipStream_t stream) {
    const float* y   = (const float*)d_in[0];
    const float* x   = (const float*)d_in[1];
    const float* f_y = (const float*)d_in[2];
    const int*   nbr = (const int*)d_in[3];
    // d_in[4] = neighbors_row_splits (uniform arange*32) -- unused
    const float* wts = (const float*)d_in[5];
    const float* W0  = (const float*)d_in[6];
    const float* b0  = (const float*)d_in[7];
    const float* W1  = (const float*)d_in[8];
    const float* b1  = (const float*)d_in[9];
    const float* W2  = (const float*)d_in[10];
    const float* b2  = (const float*)d_in[11];
    unsigned short* wp = (unsigned short*)d_ws;   // 180224 B of packed bf16 fragments
    float* out = (float*)d_out;

    pack_w<<<dim3(44), dim3(256), 0, stream>>>(W0, W1, W2, wp);
    gno_fused<<<dim3(NEDGES / TM), dim3(256), 0, stream>>>(
        y, x, f_y, nbr, wts, b0, b1, b2, wp, out);
}

// Round 7
// 290.312 us; speedup vs baseline: 1.0486x; 1.0122x over previous
//
#include <hip/hip_runtime.h>
#include <hip/hip_bf16.h>
#include <stdint.h>

#define NPTS 32768
#define KNBR 32
#define NEDGES (NPTS * KNBR)
#define TM 64           // edges per block (= 2 output rows)
#define AGG_STRIDE 40   // bf16 elems per agg row (80 B, 16B aligned)
#define H_STRIDE 264    // bf16 elems per h row (528 B, 16B aligned)

typedef __attribute__((ext_vector_type(8))) short short8;
typedef __attribute__((ext_vector_type(4))) float f32x4;
typedef __attribute__((ext_vector_type(4))) unsigned int u32x4;
typedef __attribute__((ext_vector_type(2))) unsigned int u32x2;

// round-to-nearest-even f32 -> bf16 (one-time pack kernel only)
__device__ __forceinline__ unsigned short f2bf(float f) {
    unsigned int u = __float_as_uint(f);
    unsigned int r = (u + 0x7FFFu + ((u >> 16) & 1u)) >> 16;
    return (unsigned short)r;
}

// gfx950 packed f32->bf16 (RNE), single instruction (R4-proven)
__device__ __forceinline__ unsigned int cvt_pk_bf16(float lo, float hi) {
    unsigned int r;
    asm("v_cvt_pk_bf16_f32 %0, %1, %2" : "=v"(r) : "v"(lo), "v"(hi));
    return r;
}

// jax.nn.gelu approximate=True via sigmoid identity (scalar, R4-proven):
// gelu(x) = x / (1 + exp2(x * (-2.30220824 - 0.102942496 x^2)))
__device__ __forceinline__ float gelu_tanh(float x) {
    float x2 = x * x;
    float u = fmaf(-0.102942496f, x2, -2.30220824f);
    float e = __builtin_amdgcn_exp2f(x * u);
    return x * __builtin_amdgcn_rcpf(1.0f + e);
}

// ---------------- weight packing into MFMA fragment layout (bf16) ----------------
// Fragment f: 64 lanes x 8 bf16 at wp[f*512 + l*8]; lane l supplies
// W[k0+j][col16 + (l&15)], k0 = s*32 + (l>>4)*8, j=0..7.
// Fragment order chosen so each WAVE's loads in gno_fused are contiguous:
//   f in [0,16):    W0, nt = f
//   f in [16,144):  W1, f = 16 + wn*64 + s*8 + n   (nt = wn*8+n)
//   f in [144,176): W2, f = 144 + c*8 + s          (c = output 16-col block 0..3)
__global__ void pack_w(const float* __restrict__ W0, const float* __restrict__ W1,
                       const float* __restrict__ W2, unsigned short* __restrict__ wp) {
    int tid = blockIdx.x * blockDim.x + threadIdx.x;
    if (tid >= 176 * 64) return;
    int fid = tid >> 6, l = tid & 63, ln = l & 15, lg = l >> 4;
    unsigned short v[8];
    if (fid < 16) {
        int nt = fid, k0 = lg * 8;
        #pragma unroll
        for (int j = 0; j < 8; ++j) {
            int k = k0 + j;
            v[j] = f2bf(k < 6 ? W0[k * 256 + nt * 16 + ln] : 0.0f);
        }
    } else if (fid < 144) {
        int g = fid - 16;
        int wn = g >> 6, rem = g & 63, s = rem >> 3, n = rem & 7;
        int col = (wn * 8 + n) * 16 + ln;
        int k0 = s * 32 + lg * 8;
        #pragma unroll
        for (int j = 0; j < 8; ++j) v[j] = f2bf(W1[(k0 + j) * 256 + col]);
    } else {
        int g = fid - 144;
        int c = g >> 3, s = g & 7;
        int col = c * 16 + ln;
        int k0 = s * 32 + lg * 8;
        #pragma unroll
        for (int j = 0; j < 8; ++j) v[j] = f2bf(W2[(k0 + j) * 64 + col]);
    }
    unsigned short* o = &wp[tid * 8];
    #pragma unroll
    for (int j = 0; j < 8; ++j) o[j] = v[j];
}

// ---------------- fused GNO kernel (transposed GEMMs: D = W^T * act^T) -------------
// 2x2 wave tiling: wave (wm=w&1, wn=w>>1) owns edge tiles {2wm,2wm+1} x channel half.
// All biases folded into MFMA C-operand; all addresses = 1 base + const offsets.
__global__ __launch_bounds__(256, 3)
void gno_fused(const float* __restrict__ y, const float* __restrict__ x,
               const float* __restrict__ f_y, const int* __restrict__ nbr,
               const float* __restrict__ wts,
               const float* __restrict__ b0, const float* __restrict__ b1,
               const float* __restrict__ b2,
               const unsigned short* __restrict__ wp,
               float* __restrict__ out) {
    __shared__ __align__(16) unsigned short agg_lds[TM * AGG_STRIDE];  // 5 KB
    __shared__ __align__(16) unsigned short h_lds[TM * H_STRIDE];      // 33 KB

    const int b = blockIdx.x;
    const int tid = threadIdx.x;
    const int l = tid & 63;
    const int w = tid >> 6;          // wave 0..3
    const int wm = w & 1;            // edge-tile half (out row within block)
    const int wn = w >> 1;           // channel half
    const int lg = l >> 4;           // lane group 0..3
    const int ln = l & 15;
    const int ebase = b * TM;

    // per-wave/lane weight base pointers (contiguous fragment layout)
    const char* wpb = (const char*)wp;
    const char* pW0 = wpb + wn * 8192 + l * 16;
    const char* pW1 = wpb + 16384 + wn * 65536 + l * 16;
    const char* pW2 = wpb + 147456 + wn * 16384 + l * 16;
    // LDS byte bases
    const char* aggb = (const char*)agg_lds + (wm * 32 + ln) * (AGG_STRIDE * 2) + lg * 16;
    char* hwb = (char*)h_lds + (wm * 32 + ln) * (H_STRIDE * 2) + wn * 256 + lg * 8;
    const char* hrb = (const char*)h_lds + (wm * 32 + ln) * (H_STRIDE * 2) + lg * 16;

    // ---- stage agg = [y[nbr[e]] (3), x[e>>5] (3), 0...] as bf16, K padded to 32
    if (tid < TM) {
        int e = ebase + tid;
        int j = nbr[e];
        int i = e >> 5;              // uniform CSR: row_splits = arange*32
        const float* yr = &y[j * 3];
        const float* xr = &x[i * 3];
        u32x4 q0;
        q0.x = cvt_pk_bf16(yr[0], yr[1]);
        q0.y = cvt_pk_bf16(yr[2], xr[0]);
        q0.z = cvt_pk_bf16(xr[1], xr[2]);
        q0.w = 0u;
        u32x4 z = {0u, 0u, 0u, 0u};
        unsigned short* row = &agg_lds[tid * AGG_STRIDE];
        *(u32x4*)(row +  0) = q0;
        *(u32x4*)(row +  8) = z;
        *(u32x4*)(row + 16) = z;
        *(u32x4*)(row + 24) = z;
    }
    __syncthreads();

    // ---- GEMM1: h0^T = gelu(W0^T @ agg^T + b0); bias enters as MFMA C
    {
        short8 ag[2];
        #pragma unroll
        for (int m = 0; m < 2; ++m)
            ag[m] = *(const short8*)(aggb + m * 1280);
        #pragma unroll
        for (int n = 0; n < 8; ++n) {
            short8 aw = *(const short8*)(pW0 + n * 1024);
            f32x4 b0f = *(const f32x4*)&b0[(8 * wn + n) * 16 + lg * 4];
            #pragma unroll
            for (int m = 0; m < 2; ++m) {
                f32x4 c = __builtin_amdgcn_mfma_f32_16x16x32_bf16(aw, ag[m], b0f, 0, 0, 0);
                u32x2 pv;
                pv.x = cvt_pk_bf16(gelu_tanh(c[0]), gelu_tanh(c[1]));
                pv.y = cvt_pk_bf16(gelu_tanh(c[2]), gelu_tanh(c[3]));
                *(u32x2*)(hwb + m * 8448 + n * 32) = pv;
            }
        }
    }
    __syncthreads();

    // ---- GEMM2: h1^T = gelu(W1^T @ h0^T + b1), K=256; acc init = b1 fragment
    f32x4 acc[2][8];
    #pragma unroll
    for (int n = 0; n < 8; ++n) {
        f32x4 b1f = *(const f32x4*)&b1[(8 * wn + n) * 16 + lg * 4];
        acc[0][n] = b1f;
        acc[1][n] = b1f;
    }
    #pragma unroll
    for (int s = 0; s < 8; ++s) {
        short8 hb[2];
        #pragma unroll
        for (int m = 0; m < 2; ++m)
            hb[m] = *(const short8*)(hrb + m * 8448 + s * 64);
        #pragma unroll
        for (int n = 0; n < 8; ++n) {
            short8 aw = *(const short8*)(pW1 + (s * 8 + n) * 1024);
            #pragma unroll
            for (int m = 0; m < 2; ++m)
                acc[m][n] = __builtin_amdgcn_mfma_f32_16x16x32_bf16(aw, hb[m], acc[m][n], 0, 0, 0);
        }
    }
    __syncthreads();   // all waves done READING h0 before overwriting with h1

    #pragma unroll
    for (int n = 0; n < 8; ++n) {
        #pragma unroll
        for (int m = 0; m < 2; ++m) {
            u32x2 pv;
            pv.x = cvt_pk_bf16(gelu_tanh(acc[m][n][0]), gelu_tanh(acc[m][n][1]));
            pv.y = cvt_pk_bf16(gelu_tanh(acc[m][n][2]), gelu_tanh(acc[m][n][3]));
            *(u32x2*)(hwb + m * 8448 + n * 32) = pv;
        }
    }
    __syncthreads();

    // ---- GEMM3: rep^T = W2^T @ h1^T + b2; wave does 2 edge tiles x 2 col blocks
    f32x4 acc3[2][2];
    #pragma unroll
    for (int jj = 0; jj < 2; ++jj) {
        f32x4 b2f = *(const f32x4*)&b2[(2 * wn + jj) * 16 + lg * 4];
        acc3[0][jj] = b2f;
        acc3[1][jj] = b2f;
    }
    #pragma unroll
    for (int s = 0; s < 8; ++s) {
        short8 hb[2];
        #pragma unroll
        for (int m = 0; m < 2; ++m)
            hb[m] = *(const short8*)(hrb + m * 8448 + s * 64);
        #pragma unroll
        for (int jj = 0; jj < 2; ++jj) {
            short8 aw = *(const short8*)(pW2 + (jj * 8 + s) * 1024);
            #pragma unroll
            for (int m = 0; m < 2; ++m)
                acc3[m][jj] = __builtin_amdgcn_mfma_f32_16x16x32_bf16(aw, hb[m], acc3[m][jj], 0, 0, 0);
        }
    }

    // ---- epilogue: rep * f_y[nbr] * wts, segment-sum over 32 edges/row
    // wave (wm, wn) owns out row (2b + wm), channels [32*wn, 32*wn+32)
    {
        f32x4 seg[2];
        seg[0] = (f32x4){0.f, 0.f, 0.f, 0.f};
        seg[1] = (f32x4){0.f, 0.f, 0.f, 0.f};
        #pragma unroll
        for (int m = 0; m < 2; ++m) {
            int e = ebase + (2 * wm + m) * 16 + ln;
            int j = nbr[e];
            float wt = wts[e];
            #pragma unroll
            for (int jj = 0; jj < 2; ++jj) {
                int ch = (2 * wn + jj) * 16 + lg * 4;
                f32x4 fy = *(const f32x4*)&f_y[j * 64 + ch];
                f32x4 v;
                #pragma unroll
                for (int i = 0; i < 4; ++i)
                    v[i] = acc3[m][jj][i] * fy[i] * wt;
                seg[jj] += v;
            }
        }
        #pragma unroll
        for (int jj = 0; jj < 2; ++jj) {
            f32x4 v = seg[jj];
            #pragma unroll
            for (int d = 1; d <= 8; d <<= 1) {
                #pragma unroll
                for (int i = 0; i < 4; ++i)
                    v[i] += __shfl_xor(v[i], d, 64);
            }
            if (ln == 0)
                *(f32x4*)&out[(2 * b + wm) * 64 + (2 * wn + jj) * 16 + lg * 4] = v;
        }
    }
}

extern "C" void kernel_launch(void* const* d_in, const int* in_sizes, int n_in,
                              void* d_out, int out_size, void* d_ws, size_t ws_size,
                              hipStream_t stream) {
    const float* y   = (const float*)d_in[0];
    const float* x   = (const float*)d_in[1];
    const float* f_y = (const float*)d_in[2];
    const int*   nbr = (const int*)d_in[3];
    // d_in[4] = neighbors_row_splits (uniform arange*32) -- unused
    const float* wts = (const float*)d_in[5];
    const float* W0  = (const float*)d_in[6];
    const float* b0  = (const float*)d_in[7];
    const float* W1  = (const float*)d_in[8];
    const float* b1  = (const float*)d_in[9];
    const float* W2  = (const float*)d_in[10];
    const float* b2  = (const float*)d_in[11];
    unsigned short* wp = (unsigned short*)d_ws;   // 176 KB packed bf16 fragments
    float* out = (float*)d_out;

    pack_w<<<dim3(44), dim3(256), 0, stream>>>(W0, W1, W2, wp);
    gno_fused<<<dim3(NEDGES / TM), dim3(256), 0, stream>>>(
        y, x, f_y, nbr, wts, b0, b1, b2, wp, out);
}

// Round 8
// 257.352 us; speedup vs baseline: 1.1829x; 1.1281x over previous
//
#include <hip/hip_runtime.h>
#include <hip/hip_bf16.h>
#include <stdint.h>

#define NPTS 32768
#define KNBR 32
#define NEDGES (NPTS * KNBR)
#define TM 128          // edges per block (= 4 output rows), 512 threads / 8 waves
#define AGG_STRIDE 40   // bf16 elems per agg row (80 B)
#define H_STRIDE 264    // bf16 elems per h row (528 B)

typedef __attribute__((ext_vector_type(8))) short short8;
typedef __attribute__((ext_vector_type(4))) float f32x4;
typedef __attribute__((ext_vector_type(4))) unsigned int u32x4;
typedef __attribute__((ext_vector_type(2))) unsigned int u32x2;

// round-to-nearest-even f32 -> bf16 (one-time pack kernel only)
__device__ __forceinline__ unsigned short f2bf(float f) {
    unsigned int u = __float_as_uint(f);
    unsigned int r = (u + 0x7FFFu + ((u >> 16) & 1u)) >> 16;
    return (unsigned short)r;
}

// gfx950 packed f32->bf16 (RNE), single instruction (R4-proven)
__device__ __forceinline__ unsigned int cvt_pk_bf16(float lo, float hi) {
    unsigned int r;
    asm("v_cvt_pk_bf16_f32 %0, %1, %2" : "=v"(r) : "v"(lo), "v"(hi));
    return r;
}

// jax.nn.gelu approximate=True via sigmoid identity (scalar, proven):
// gelu(x) = x / (1 + exp2(x * (-2.30220824 - 0.102942496 x^2)))
__device__ __forceinline__ float gelu_tanh(float x) {
    float x2 = x * x;
    float u = fmaf(-0.102942496f, x2, -2.30220824f);
    float e = __builtin_amdgcn_exp2f(x * u);
    return x * __builtin_amdgcn_rcpf(1.0f + e);
}

// ---------------- weight packing into MFMA fragment layout (bf16) ----------------
// Fragment f (1KB): lane l supplies W[k0+j][col16 + (l&15)], k0 = s*32 + (l>>4)*8.
//   f in [0,16):    W0, nt = f
//   f in [16,144):  W1, f = 16 + nt*8 + s      (nt-major: per-wave 16KB contiguous)
//   f in [144,176): W2, f = 144 + c*8 + s      (c = output 16-col block 0..3)
__global__ void pack_w(const float* __restrict__ W0, const float* __restrict__ W1,
                       const float* __restrict__ W2, unsigned short* __restrict__ wp) {
    int tid = blockIdx.x * blockDim.x + threadIdx.x;
    if (tid >= 176 * 64) return;
    int fid = tid >> 6, l = tid & 63, ln = l & 15, lg = l >> 4;
    unsigned short v[8];
    if (fid < 16) {
        int nt = fid, k0 = lg * 8;
        #pragma unroll
        for (int j = 0; j < 8; ++j) {
            int k = k0 + j;
            v[j] = f2bf(k < 6 ? W0[k * 256 + nt * 16 + ln] : 0.0f);
        }
    } else if (fid < 144) {
        int g = fid - 16;
        int nt = g >> 3, s = g & 7;
        int col = nt * 16 + ln;
        int k0 = s * 32 + lg * 8;
        #pragma unroll
        for (int j = 0; j < 8; ++j) v[j] = f2bf(W1[(k0 + j) * 256 + col]);
    } else {
        int g = fid - 144;
        int c = g >> 3, s = g & 7;
        int col = c * 16 + ln;
        int k0 = s * 32 + lg * 8;
        #pragma unroll
        for (int j = 0; j < 8; ++j) v[j] = f2bf(W2[(k0 + j) * 64 + col]);
    }
    unsigned short* o = &wp[tid * 8];
    #pragma unroll
    for (int j = 0; j < 8; ++j) o[j] = v[j];
}

// ---------------- fused GNO kernel (transposed GEMMs: D = W^T * act^T) -------------
// 8 waves. GEMM1/2: wave w owns ntiles {2w, 2w+1} x ALL 8 edge-tiles (weight frags
// loaded ~once per block). GEMM3/epilogue: wave w owns edge half wm=w&1 (4 mt) x
// c-tile wc=w>>1. f_y/wts prefetched before GEMM3 (latency hides under MFMA).
__global__ __launch_bounds__(512, 4)
void gno_fused(const float* __restrict__ y, const float* __restrict__ x,
               const float* __restrict__ f_y, const int* __restrict__ nbr,
               const float* __restrict__ wts,
               const float* __restrict__ b0, const float* __restrict__ b1,
               const float* __restrict__ b2,
               const unsigned short* __restrict__ wp,
               float* __restrict__ out) {
    __shared__ __align__(16) unsigned short agg_lds[TM * AGG_STRIDE];  // 10.2 KB
    __shared__ __align__(16) unsigned short h_lds[TM * H_STRIDE];      // 67.6 KB

    const int b = blockIdx.x;
    const int tid = threadIdx.x;
    const int l = tid & 63;
    const int w = tid >> 6;          // wave 0..7
    const int wm = w & 1;            // edge half (GEMM3/epilogue)
    const int wc = w >> 1;           // c-tile 0..3 (GEMM3/epilogue)
    const int lg = l >> 4;
    const int ln = l & 15;
    const int ebase = b * TM;

    // weight base pointers (contiguous per-wave fragment runs)
    const char* wpb = (const char*)wp;
    const char* pW0 = wpb + w * 2048 + l * 16;             // nt=2w at +0, 2w+1 at +1024
    const char* pW1 = wpb + 16384 + w * 16384 + l * 16;    // (n,s) at + n*8192 + s*1024
    const char* pW2 = wpb + 147456 + wc * 8192 + l * 16;   // s at + s*1024
    // LDS byte bases
    const char* aggb = (const char*)agg_lds + ln * 80 + lg * 16;      // mt at +mt*1280
    char* hwb = (char*)h_lds + ln * 528 + w * 64 + lg * 8;            // (mt,n): +mt*8448+n*32
    const char* hrb = (const char*)h_lds + ln * 528 + lg * 16;        // (mt,s): +mt*8448+s*64

    // ---- stage agg = [y[nbr[e]] (3), x[e>>5] (3), 0...] as bf16, K padded to 32
    if (tid < TM) {
        int e = ebase + tid;
        int j = nbr[e];
        int i = e >> 5;              // uniform CSR: row_splits = arange*32
        const float* yr = &y[j * 3];
        const float* xr = &x[i * 3];
        u32x4 q0;
        q0.x = cvt_pk_bf16(yr[0], yr[1]);
        q0.y = cvt_pk_bf16(yr[2], xr[0]);
        q0.z = cvt_pk_bf16(xr[1], xr[2]);
        q0.w = 0u;
        u32x4 z = {0u, 0u, 0u, 0u};
        unsigned short* row = &agg_lds[tid * AGG_STRIDE];
        *(u32x4*)(row +  0) = q0;
        *(u32x4*)(row +  8) = z;
        *(u32x4*)(row + 16) = z;
        *(u32x4*)(row + 24) = z;
    }
    __syncthreads();

    // ---- GEMM1: h0^T = gelu(W0^T @ agg^T + b0); wave w: ntiles {2w,2w+1} x 8 mt
    {
        short8 aw0 = *(const short8*)(pW0);
        short8 aw1 = *(const short8*)(pW0 + 1024);
        f32x4 b0f0 = *(const f32x4*)&b0[(2 * w) * 16 + lg * 4];
        f32x4 b0f1 = *(const f32x4*)&b0[(2 * w + 1) * 16 + lg * 4];
        #pragma unroll
        for (int mt = 0; mt < 8; ++mt) {
            short8 ag = *(const short8*)(aggb + mt * 1280);
            f32x4 c0 = __builtin_amdgcn_mfma_f32_16x16x32_bf16(aw0, ag, b0f0, 0, 0, 0);
            f32x4 c1 = __builtin_amdgcn_mfma_f32_16x16x32_bf16(aw1, ag, b0f1, 0, 0, 0);
            u32x2 p0, p1;
            p0.x = cvt_pk_bf16(gelu_tanh(c0[0]), gelu_tanh(c0[1]));
            p0.y = cvt_pk_bf16(gelu_tanh(c0[2]), gelu_tanh(c0[3]));
            p1.x = cvt_pk_bf16(gelu_tanh(c1[0]), gelu_tanh(c1[1]));
            p1.y = cvt_pk_bf16(gelu_tanh(c1[2]), gelu_tanh(c1[3]));
            *(u32x2*)(hwb + mt * 8448)      = p0;
            *(u32x2*)(hwb + mt * 8448 + 32) = p1;
        }
    }
    __syncthreads();

    // ---- GEMM2: h1^T = gelu(W1^T @ h0^T + b1), K=256; acc[8 mt][2 nt] (AGPR)
    f32x4 acc[8][2];
    {
        f32x4 b1f0 = *(const f32x4*)&b1[(2 * w) * 16 + lg * 4];
        f32x4 b1f1 = *(const f32x4*)&b1[(2 * w + 1) * 16 + lg * 4];
        #pragma unroll
        for (int mt = 0; mt < 8; ++mt) { acc[mt][0] = b1f0; acc[mt][1] = b1f1; }
    }
    #pragma unroll
    for (int s = 0; s < 8; ++s) {
        short8 aw0 = *(const short8*)(pW1 + s * 1024);
        short8 aw1 = *(const short8*)(pW1 + 8192 + s * 1024);
        #pragma unroll
        for (int mt = 0; mt < 8; ++mt) {
            short8 hb = *(const short8*)(hrb + mt * 8448 + s * 64);
            acc[mt][0] = __builtin_amdgcn_mfma_f32_16x16x32_bf16(aw0, hb, acc[mt][0], 0, 0, 0);
            acc[mt][1] = __builtin_amdgcn_mfma_f32_16x16x32_bf16(aw1, hb, acc[mt][1], 0, 0, 0);
        }
    }
    __syncthreads();   // all waves done READING h0 before overwriting with h1

    #pragma unroll
    for (int mt = 0; mt < 8; ++mt) {
        #pragma unroll
        for (int n = 0; n < 2; ++n) {
            u32x2 pv;
            pv.x = cvt_pk_bf16(gelu_tanh(acc[mt][n][0]), gelu_tanh(acc[mt][n][1]));
            pv.y = cvt_pk_bf16(gelu_tanh(acc[mt][n][2]), gelu_tanh(acc[mt][n][3]));
            *(u32x2*)(hwb + mt * 8448 + n * 32) = pv;
        }
    }
    __syncthreads();

    // ---- prefetch f_y / wts for epilogue (latency hides under GEMM3's MFMAs)
    f32x4 fy[4];
    float wv[4];
    #pragma unroll
    for (int m = 0; m < 4; ++m) {
        int e = ebase + (wm * 4 + m) * 16 + ln;
        int j = nbr[e];
        fy[m] = *(const f32x4*)&f_y[j * 64 + wc * 16 + lg * 4];
        wv[m] = wts[e];
    }

    // ---- GEMM3: rep^T = W2^T @ h1^T + b2; wave: 4 mt (edge half) x 1 c-tile
    f32x4 acc3[4];
    {
        f32x4 b2f = *(const f32x4*)&b2[wc * 16 + lg * 4];
        #pragma unroll
        for (int m = 0; m < 4; ++m) acc3[m] = b2f;
    }
    const char* hrb3 = hrb + wm * 33792;   // wm*4 mt offset (4*8448)
    #pragma unroll
    for (int s = 0; s < 8; ++s) {
        short8 aw = *(const short8*)(pW2 + s * 1024);
        #pragma unroll
        for (int m = 0; m < 4; ++m) {
            short8 hb = *(const short8*)(hrb3 + m * 8448 + s * 64);
            acc3[m] = __builtin_amdgcn_mfma_f32_16x16x32_bf16(aw, hb, acc3[m], 0, 0, 0);
        }
    }

    // ---- epilogue: rep * f_y[nbr] * wts, segment-sum (32 edges per out row)
    {
        f32x4 seg[2];
        seg[0] = (f32x4){0.f, 0.f, 0.f, 0.f};
        seg[1] = (f32x4){0.f, 0.f, 0.f, 0.f};
        #pragma unroll
        for (int m = 0; m < 4; ++m) {
            f32x4 v;
            #pragma unroll
            for (int i = 0; i < 4; ++i)
                v[i] = acc3[m][i] * fy[m][i] * wv[m];
            seg[m >> 1] += v;
        }
        #pragma unroll
        for (int g = 0; g < 2; ++g) {
            f32x4 v = seg[g];
            #pragma unroll
            for (int d = 1; d <= 8; d <<= 1) {
                #pragma unroll
                for (int i = 0; i < 4; ++i)
                    v[i] += __shfl_xor(v[i], d, 64);
            }
            if (ln == 0)
                *(f32x4*)&out[(b * 4 + wm * 2 + g) * 64 + wc * 16 + lg * 4] = v;
        }
    }
}

extern "C" void kernel_launch(void* const* d_in, const int* in_sizes, int n_in,
                              void* d_out, int out_size, void* d_ws, size_t ws_size,
                              hipStream_t stream) {
    const float* y   = (const float*)d_in[0];
    const float* x   = (const float*)d_in[1];
    const float* f_y = (const float*)d_in[2];
    const int*   nbr = (const int*)d_in[3];
    // d_in[4] = neighbors_row_splits (uniform arange*32) -- unused
    const float* wts = (const float*)d_in[5];
    const float* W0  = (const float*)d_in[6];
    const float* b0  = (const float*)d_in[7];
    const float* W1  = (const float*)d_in[8];
    const float* b1  = (const float*)d_in[9];
    const float* W2  = (const float*)d_in[10];
    const float* b2  = (const float*)d_in[11];
    unsigned short* wp = (unsigned short*)d_ws;   // 176 KB packed bf16 fragments
    float* out = (float*)d_out;

    pack_w<<<dim3(44), dim3(256), 0, stream>>>(W0, W1, W2, wp);
    gno_fused<<<dim3(NEDGES / TM), dim3(512), 0, stream>>>(
        y, x, f_y, nbr, wts, b0, b1, b2, wp, out);
}